// Round 15
// baseline (1530.221 us; speedup 1.0000x reference)
//
#include <hip/hip_runtime.h>
#include <stdint.h>

#define B_ 64
#define S_ 512
#define T_ 12
#define M_ (B_*S_)      // 32768 rows
#define NP_ 2048        // width of per-step projection P

typedef __attribute__((ext_vector_type(8))) short bf16x8;   // 8 bf16 = 4 VGPR
typedef __attribute__((ext_vector_type(4))) float f32x4;    // MFMA accumulator

__device__ __forceinline__ uint16_t f2bf(float f){
  union { float f; uint32_t u; } x; x.f = f;
  uint32_t r = x.u + 0x7FFFu + ((x.u >> 16) & 1u);   // RTNE
  return (uint16_t)(r >> 16);
}
__device__ __forceinline__ float bf2f(uint16_t u){
  union { float f; uint32_t u; } x; x.u = ((uint32_t)u) << 16; return x.f;
}
__device__ __forceinline__ float sigm(float x){ return 1.0f/(1.0f + expf(-x)); }
__device__ __forceinline__ float4 bf4(const uint16_t* p){
  const ushort4 v = *reinterpret_cast<const ushort4*>(p);
  return make_float4(bf2f(v.x), bf2f(v.y), bf2f(v.z), bf2f(v.w));
}

// async global->LDS, 16B per lane; LDS dest = wave-uniform base + lane*16
__device__ __forceinline__ void gload16(const uint16_t* g, uint16_t* l){
  __builtin_amdgcn_global_load_lds(
      (const __attribute__((address_space(1))) uint32_t*)g,
      (__attribute__((address_space(3))) uint32_t*)l, 16, 0, 0);
}

// ---------------------------------------------------------------------------
__global__ void zero16(uint4* __restrict__ p, long n16){
  const long i = (long)blockIdx.x * 256 + threadIdx.x;
  if (i < n16) p[i] = make_uint4(0,0,0,0);
}
__global__ void bf16_to_f32(const uint16_t* __restrict__ src, float* __restrict__ dst, long n){
  const long i = ((long)blockIdx.x * 256 + threadIdx.x) * 4;
  if (i + 3 < n) {
    const float4 o = bf4(src + i);
    *reinterpret_cast<float4*>(dst + i) = o;
  }
}

// ---------------------------------------------------------------------------
// UcatT[2048][256] bf16, UcatT[n][k] = [U_iou_r | U_iou_l | U_f0+U_f1 | U_f2+U_f3][k][n]
__global__ void build_ucatT(const float* __restrict__ Ur, const float* __restrict__ Ul,
                            const float* __restrict__ f0, const float* __restrict__ f1,
                            const float* __restrict__ f2, const float* __restrict__ f3,
                            uint16_t* __restrict__ UcatT){
  const int idx = blockIdx.x * 256 + threadIdx.x;   // 2048*256 total
  const int n = idx >> 8, k = idx & 255;
  float v;
  if (n < 768)        v = Ur[k*768 + n];
  else if (n < 1536)  v = Ul[k*768 + (n-768)];
  else if (n < 1792) { int j = n-1536; v = f0[k*256+j] + f1[k*256+j]; }
  else               { int j = n-1792; v = f2[k*256+j] + f3[k*256+j]; }
  UcatT[(long)n*256 + k] = f2bf(v);
}

// WallT[1024][256] bf16 = [W_ioux | W_f]^T   (grid = 1024, 256 threads)
__global__ void build_wallT(const float* __restrict__ Wioux, const float* __restrict__ Wf,
                            uint16_t* __restrict__ WT){
  const int idx = blockIdx.x * 256 + threadIdx.x;   // 1024*256 total
  const int n = idx >> 8, k = idx & 255;
  const float v = (n < 768) ? Wioux[(long)k*768 + n] : Wf[(long)k*256 + (n-768)];
  WT[(long)n*256 + k] = f2bf(v);
}

// embg[M][256] bf16 = emb[input_ids[r]][k]  (gather + convert; 1 wave/row)
__global__ void gather_embg(const float* __restrict__ emb, const int* __restrict__ ids,
                            uint16_t* __restrict__ out){
  const int wave = threadIdx.x >> 6, lane = threadIdx.x & 63;
  const long row = (long)blockIdx.x*4 + wave;
  const long rid = (long)ids[row];
  const float4 v = *reinterpret_cast<const float4*>(emb + rid*256 + lane*4);
  ushort4 o; o.x=f2bf(v.x); o.y=f2bf(v.y); o.z=f2bf(v.z); o.w=f2bf(v.w);
  *reinterpret_cast<ushort4*>(out + row*256 + lane*4) = o;
}

// ---------------------------------------------------------------------------
// Setup-path MFMA GEMM (bf16 A, K=256, row-major C): 2-buffer counted-vmcnt
// pipeline, XOR seg-swizzle, XCD-pinned m-tiles, coalesced C via LDS restage.
__global__ __launch_bounds__(256)
void gemm_pipe(const uint16_t* __restrict__ A, const uint16_t* __restrict__ BT,
               const float* __restrict__ bias, const float* __restrict__ bias2, int split,
               uint16_t* __restrict__ C, int N, int NT)
{
  __shared__ __align__(16) uint16_t smem[16384];   // A0|A1|B0|B1 (4096 u16 each) = 32 KB
  const int tid = threadIdx.x, lane = tid & 63, wave = tid >> 6;
  const int wr = wave >> 1, wc = wave & 1;
  const int id = blockIdx.x, rx = id & 7, q = id >> 3;
  const int mt = rx + 8*(q / NT);
  const int nt = q % NT;
  const long m0 = (long)mt * 128;
  const int  n0 = nt * 128;

  const int rl0 = wave*32 + (lane >> 2);
  const int rl1 = rl0 + 16;
  const int sg0 = (lane & 3) ^ ((rl0 >> 1) & 3);
  const int sg1 = (lane & 3) ^ ((rl1 >> 1) & 3);
  const uint16_t* ga0 = A + (m0 + rl0)*256 + sg0*8;
  const uint16_t* ga1 = A + (m0 + rl1)*256 + sg1*8;
  const uint16_t* gb0 = BT + (long)(n0 + rl0)*256 + sg0*8;
  const uint16_t* gb1 = BT + (long)(n0 + rl1)*256 + sg1*8;

  f32x4 acc[4][4];
  #pragma unroll
  for (int i=0;i<4;i++)
    #pragma unroll
    for (int j=0;j<4;j++) acc[i][j] = (f32x4){0.f,0.f,0.f,0.f};

  const int l15 = lane & 15, lseg = lane >> 4;
  int aoff[4], boff[4];
  #pragma unroll
  for (int i=0;i<4;i++){ const int m = wr*64 + i*16 + l15; aoff[i] = m*32 + ((lseg ^ ((m>>1)&3))<<3); }
  #pragma unroll
  for (int j=0;j<4;j++){ const int n = wc*64 + j*16 + l15; boff[j] = n*32 + ((lseg ^ ((n>>1)&3))<<3); }

  #define STAGE(tile, buf) {                                   \
    const int ks_ = (tile)*32;                                 \
    uint16_t* a_ = &smem[(buf)*4096 + wave*1024];              \
    uint16_t* b_ = &smem[8192 + (buf)*4096 + wave*1024];       \
    gload16(ga0 + ks_, a_); gload16(ga1 + ks_, a_ + 512);      \
    gload16(gb0 + ks_, b_); gload16(gb1 + ks_, b_ + 512);      \
  }

  STAGE(0, 0)
  STAGE(1, 1)

  #pragma unroll
  for (int tt = 0; tt < 8; ++tt) {
    if (tt < 7) asm volatile("s_waitcnt vmcnt(4)" ::: "memory");
    else        asm volatile("s_waitcnt vmcnt(0)" ::: "memory");
    __builtin_amdgcn_s_barrier();
    const int cb = tt & 1;
    bf16x8 af[4], bfv[4];
    #pragma unroll
    for (int i=0;i<4;i++) af[i]  = *reinterpret_cast<const bf16x8*>(&smem[cb*4096 + aoff[i]]);
    #pragma unroll
    for (int j=0;j<4;j++) bfv[j] = *reinterpret_cast<const bf16x8*>(&smem[8192 + cb*4096 + boff[j]]);
    __builtin_amdgcn_s_setprio(1);
    #pragma unroll
    for (int i=0;i<4;i++)
      #pragma unroll
      for (int j=0;j<4;j++)
        acc[i][j] = __builtin_amdgcn_mfma_f32_16x16x32_bf16(af[i], bfv[j], acc[i][j], 0, 0, 0);
    __builtin_amdgcn_s_setprio(0);
    if (tt < 6) {
      __builtin_amdgcn_s_barrier();
      STAGE(tt + 2, cb)
    }
  }
  #undef STAGE

  __syncthreads();
  const int rquad = lane >> 4;
  const int rowq = tid >> 4;
  const int cseg = tid & 15;
  float bv[4];
  #pragma unroll
  for (int j=0;j<4;j++){
    const int col = n0 + wc*64 + j*16 + l15;
    bv[j] = bias ? ((col < split) ? bias[col] : bias2[col - split]) : 0.0f;
  }
  #pragma unroll
  for (int half = 0; half < 2; ++half) {
    if (wr == half) {
      #pragma unroll
      for (int i=0;i<4;i++)
        #pragma unroll
        for (int j=0;j<4;j++)
          #pragma unroll
          for (int r=0;r<4;r++)
            smem[(i*16 + rquad*4 + r)*136 + wc*64 + j*16 + l15] = f2bf(acc[i][j][r] + bv[j]);
    }
    __syncthreads();
    #pragma unroll
    for (int it=0; it<4; ++it) {
      const int r2 = it*16 + rowq;
      const uint4 v = *reinterpret_cast<const uint4*>(&smem[r2*136 + cseg*8]);
      *reinterpret_cast<uint4*>(C + (m0 + half*64 + r2)*N + n0 + cseg*8) = v;
    }
    __syncthreads();
  }
}

// ---------------------------------------------------------------------------
// Step-path MFMA GEMM -> TILE-BLOCKED P: P[(mt*16+nt)][128][128] bf16, each
// block writes contiguous 32 KiB per tile. 2 n-tiles per block (nt, nt+8).
// grid = (Mc/128)*8 = Mc/16.  NT fixed = 16 (N = 2048).
__global__ __launch_bounds__(256)
void gemm_step_blk(const uint16_t* __restrict__ A, const uint16_t* __restrict__ BT,
                   uint16_t* __restrict__ P)
{
  __shared__ __align__(16) uint16_t smem[16384];
  const int tid = threadIdx.x, lane = tid & 63, wave = tid >> 6;
  const int wr = wave >> 1, wc = wave & 1;
  const int mt8 = gridDim.x >> 6;                 // (Mc/128)/8
  const int id = blockIdx.x, rx = id & 7, q = id >> 3;
  const int ntp = q / mt8;                        // [0,8)
  const int mq  = q - ntp*mt8;                    // [0,mt8)
  const int mt  = rx + 8*mq;                      // XCD-pinned m-tile
  const long m0 = (long)mt * 128;

  const int rl0 = wave*32 + (lane >> 2);
  const int rl1 = rl0 + 16;
  const int sg0 = (lane & 3) ^ ((rl0 >> 1) & 3);
  const int sg1 = (lane & 3) ^ ((rl1 >> 1) & 3);
  const uint16_t* ga0 = A + (m0 + rl0)*256 + sg0*8;
  const uint16_t* ga1 = A + (m0 + rl1)*256 + sg1*8;

  const int l15 = lane & 15, lseg = lane >> 4;
  int aoff[4], boff[4];
  #pragma unroll
  for (int i=0;i<4;i++){ const int m = wr*64 + i*16 + l15; aoff[i] = m*32 + ((lseg ^ ((m>>1)&3))<<3); }
  #pragma unroll
  for (int j=0;j<4;j++){ const int n = wc*64 + j*16 + l15; boff[j] = n*32 + ((lseg ^ ((n>>1)&3))<<3); }

  const int rquad = lane >> 4;
  const int rowq = tid >> 4;
  const int cseg = tid & 15;

  #pragma unroll
  for (int t2 = 0; t2 < 2; ++t2) {
    const int nt = ntp + t2*8;
    const int n0 = nt * 128;
    const uint16_t* gb0 = BT + (long)(n0 + rl0)*256 + sg0*8;
    const uint16_t* gb1 = BT + (long)(n0 + rl1)*256 + sg1*8;

    f32x4 acc[4][4];
    #pragma unroll
    for (int i=0;i<4;i++)
      #pragma unroll
      for (int j=0;j<4;j++) acc[i][j] = (f32x4){0.f,0.f,0.f,0.f};

    #define STAGE(tile, buf) {                                   \
      const int ks_ = (tile)*32;                                 \
      uint16_t* a_ = &smem[(buf)*4096 + wave*1024];              \
      uint16_t* b_ = &smem[8192 + (buf)*4096 + wave*1024];       \
      gload16(ga0 + ks_, a_); gload16(ga1 + ks_, a_ + 512);      \
      gload16(gb0 + ks_, b_); gload16(gb1 + ks_, b_ + 512);      \
    }

    STAGE(0, 0)
    STAGE(1, 1)

    #pragma unroll
    for (int tt = 0; tt < 8; ++tt) {
      if (tt < 7) asm volatile("s_waitcnt vmcnt(4)" ::: "memory");
      else        asm volatile("s_waitcnt vmcnt(0)" ::: "memory");
      __builtin_amdgcn_s_barrier();
      const int cb = tt & 1;
      bf16x8 af[4], bfv[4];
      #pragma unroll
      for (int i=0;i<4;i++) af[i]  = *reinterpret_cast<const bf16x8*>(&smem[cb*4096 + aoff[i]]);
      #pragma unroll
      for (int j=0;j<4;j++) bfv[j] = *reinterpret_cast<const bf16x8*>(&smem[8192 + cb*4096 + boff[j]]);
      __builtin_amdgcn_s_setprio(1);
      #pragma unroll
      for (int i=0;i<4;i++)
        #pragma unroll
        for (int j=0;j<4;j++)
          acc[i][j] = __builtin_amdgcn_mfma_f32_16x16x32_bf16(af[i], bfv[j], acc[i][j], 0, 0, 0);
      __builtin_amdgcn_s_setprio(0);
      if (tt < 6) {
        __builtin_amdgcn_s_barrier();
        STAGE(tt + 2, cb)
      }
    }
    #undef STAGE

    // epilogue: contiguous 32 KiB per tile: P + (mt*16+nt)*16384
    __syncthreads();
    uint16_t* dst = P + ((long)(mt*16 + nt) << 14);
    #pragma unroll
    for (int half = 0; half < 2; ++half) {
      if (wr == half) {
        #pragma unroll
        for (int i=0;i<4;i++)
          #pragma unroll
          for (int j=0;j<4;j++)
            #pragma unroll
            for (int r=0;r<4;r++)
              smem[(i*16 + rquad*4 + r)*136 + wc*64 + j*16 + l15] = f2bf(acc[i][j][r]);
      }
      __syncthreads();
      #pragma unroll
      for (int it=0; it<4; ++it) {
        const int r2 = it*16 + rowq;
        const uint4 v = *reinterpret_cast<const uint4*>(&smem[r2*136 + cseg*8]);
        *reinterpret_cast<uint4*>(dst + (half*64 + r2)*128 + cseg*8) = v;
      }
      __syncthreads();
    }
  }
}

// ---------------------------------------------------------------------------
// Deterministic CSR inversion, chunked-histogram rank (no serial section).
__global__ void build_csr(const int* __restrict__ td_g, const int* __restrict__ tr_g,
                          const int* __restrict__ tl_g,
                          int* __restrict__ csr_off, int* __restrict__ csr_val){
  const int t = blockIdx.x >> 6;
  const int b = blockIdx.x & 63;
  __shared__ int ids[S_];
  __shared__ int cnt[S_];
  __shared__ int off[S_];
  __shared__ int chc[8][S_];
  const int s = threadIdx.x;
  const int q = s >> 6;
  const int* srcs[3] = {td_g, tr_g, tl_g};
  for (int arr = 0; arr < 3; ++arr) {
    const int myid = srcs[arr][((long)b*T_ + t)*S_ + s];
    ids[s] = myid;
    cnt[s] = 0;
    #pragma unroll
    for (int qq=0; qq<8; qq++) chc[qq][s] = 0;
    __syncthreads();
    atomicAdd(&cnt[myid], 1);
    atomicAdd(&chc[q][myid], 1);
    __syncthreads();
    int rank = 0;
    for (int qq = 0; qq < q; ++qq) rank += chc[qq][myid];
    for (int i = q*64; i < s; ++i) rank += (ids[i] == myid) ? 1 : 0;
    off[s] = cnt[s];
    __syncthreads();
    for (int w = 1; w < S_; w <<= 1){
      const int v = (s >= w) ? off[s-w] : 0;
      __syncthreads();
      off[s] += v;
      __syncthreads();
    }
    const long base = (((long)arr*T_ + t)*B_ + b);
    int* offs = csr_off + base*(S_+1);
    int* vals = csr_val + base*S_;
    offs[s] = off[s] - cnt[s];
    if (s == S_-1) offs[S_] = off[s];
    vals[(off[myid] - cnt[myid]) + rank] = s;
    __syncthreads();
  }
}

// ---------------------------------------------------------------------------
// t=0 special case: h=c=0 -> P=0 and f*c terms vanish.
__global__ __launch_bounds__(256)
void t0_update(uint16_t* __restrict__ h, uint16_t* __restrict__ c_out,
               const uint16_t* __restrict__ ioufx, const int* __restrict__ csr_off)
{
  const int wave = threadIdx.x >> 6, lane = threadIdx.x & 63;
  const long bs = (long)blockIdx.x*4 + wave;
  const int b = (int)(bs >> 9), s = (int)(bs & 511);
  const int j = lane * 4;
  const int* off_td = csr_off + (long)b*(S_+1);
  if (s == 0 || off_td[s+1] <= off_td[s]) return;
  const long ib = bs*1024;
  const float4 ai = bf4(ioufx + ib + j);
  const float4 ao = bf4(ioufx + ib + 256 + j);
  const float4 au = bf4(ioufx + ib + 512 + j);
  float4 cacc;
  cacc.x = sigm(ai.x)*tanhf(au.x); cacc.y = sigm(ai.y)*tanhf(au.y);
  cacc.z = sigm(ai.z)*tanhf(au.z); cacc.w = sigm(ai.w)*tanhf(au.w);
  ushort4 ho, co;
  ho.x = f2bf(sigm(ao.x)*tanhf(cacc.x)); ho.y = f2bf(sigm(ao.y)*tanhf(cacc.y));
  ho.z = f2bf(sigm(ao.z)*tanhf(cacc.z)); ho.w = f2bf(sigm(ao.w)*tanhf(cacc.w));
  co.x = f2bf(cacc.x); co.y = f2bf(cacc.y); co.z = f2bf(cacc.z); co.w = f2bf(cacc.w);
  *reinterpret_cast<ushort4*>(h + bs*256 + j) = ho;
  *reinterpret_cast<ushort4*>(c_out + bs*256 + j) = co;
}

// ---------------------------------------------------------------------------
// Per-step destination-side update; P is TILE-BLOCKED [(lr>>7)*16 + (c>>7)][lr&127][c&127].
// 1 wave per row, lane owns 4 channels; XCD-pinned per batch-element.
__global__ __launch_bounds__(256)
void step_update(uint16_t* __restrict__ h,
                 const uint16_t* __restrict__ c_in, uint16_t* __restrict__ c_out,
                 const uint16_t* __restrict__ P,      // blocked, chunk-local rows
                 const uint16_t* __restrict__ ioufx,  // [M][1024] bf16: i|o|u|fx
                 const int* __restrict__ csr_off, const int* __restrict__ csr_val,
                 const int* __restrict__ tr_g, const int* __restrict__ tl_g,
                 int t, int row0)
{
  const int wave = threadIdx.x >> 6, lane = threadIdx.x & 63;
  const int id = blockIdx.x, rx = id & 7, q = id >> 3;
  const int b_local = rx + 8*(q >> 7);
  const int rg = q & 127;
  const long bs = (long)row0 + b_local*512 + rg*4 + wave;
  const int b = (int)(bs >> 9), s = (int)(bs & 511);
  const int j = lane * 4;

  const int* off_td = csr_off + (((long)0*T_ + t)*B_ + b)*(S_+1);
  const int td0 = off_td[s], td1 = off_td[s+1];
  const bool masked = (s != 0) && (td1 > td0);
  if (!masked) {
    *reinterpret_cast<ushort4*>(c_out + bs*256 + j) =
        *reinterpret_cast<const ushort4*>(c_in + bs*256 + j);
    return;
  }
  const int* off_tr = csr_off + (((long)1*T_ + t)*B_ + b)*(S_+1);
  const int* off_tl = csr_off + (((long)2*T_ + t)*B_ + b)*(S_+1);
  const int* val_td = csr_val + (((long)0*T_ + t)*B_ + b)*S_;
  const int* val_tr = csr_val + (((long)1*T_ + t)*B_ + b)*S_;
  const int* val_tl = csr_val + (((long)2*T_ + t)*B_ + b)*S_;

  const long lbase = (long)(b<<9) - row0;             // chunk-local row base

  // blocked-P accessor: lr = chunk-local row, s8 = c0>>7 (c0 = 128*s8)
  const int seg_add = lane >> 5;                      // col 128-segment from lane
  const int cix = (lane & 31) * 4;
  #define PP(lr, s8) (P + ((((long)((lr)>>7)<<4) + (s8) + seg_add)<<14) + (((lr)&127)<<7) + cix)

  const long ib = bs*1024;
  float4 ai = bf4(ioufx + ib + j);
  float4 ao = bf4(ioufx + ib + 256 + j);
  float4 au = bf4(ioufx + ib + 512 + j);
  for (int p = off_tr[s]; p < off_tr[s+1]; ++p) {     // sources s' with tr[s']==s
    const long lr = lbase + val_tr[p];
    const float4 x = bf4(PP(lr,0)), y = bf4(PP(lr,2)), z = bf4(PP(lr,4));
    ai.x+=x.x; ai.y+=x.y; ai.z+=x.z; ai.w+=x.w;
    ao.x+=y.x; ao.y+=y.y; ao.z+=y.z; ao.w+=y.w;
    au.x+=z.x; au.y+=z.y; au.z+=z.z; au.w+=z.w;
  }
  for (int p = off_tl[s]; p < off_tl[s+1]; ++p) {     // sources s' with tl[s']==s
    const long lr = lbase + val_tl[p];
    const float4 x = bf4(PP(lr,6)), y = bf4(PP(lr,8)), z = bf4(PP(lr,10));
    ai.x+=x.x; ai.y+=x.y; ai.z+=x.z; ai.w+=x.w;
    ao.x+=y.x; ao.y+=y.y; ao.z+=y.z; ao.w+=y.w;
    au.x+=z.x; au.y+=z.y; au.z+=z.z; au.w+=z.w;
  }
  float4 cacc;
  cacc.x = sigm(ai.x)*tanhf(au.x); cacc.y = sigm(ai.y)*tanhf(au.y);
  cacc.z = sigm(ai.z)*tanhf(au.z); cacc.w = sigm(ai.w)*tanhf(au.w);
  const float4 fxv = bf4(ioufx + ib + 768 + j);       // f_x at the DESTINATION row
  const int* trrow = tr_g + ((long)b*T_ + t)*S_;
  const int* tlrow = tl_g + ((long)b*T_ + t)*S_;
  for (int p = td0; p < td1; ++p) {                   // children s' with td[s']==s
    const int sp = val_td[p];
    const long lrr = lbase + trrow[sp];               // P_f01 at tr[s'] (seg 12)
    const long lrl = lbase + tlrow[sp];               // P_f23 at tl[s'] (seg 14)
    const float4 pa = bf4(PP(lrr,12)), pb = bf4(PP(lrl,14));
    const float4 cv = bf4(c_in + ((long)(b<<9) + sp)*256 + j);
    cacc.x += sigm(fxv.x + pa.x + pb.x) * cv.x;
    cacc.y += sigm(fxv.y + pa.y + pb.y) * cv.y;
    cacc.z += sigm(fxv.z + pa.z + pb.z) * cv.z;
    cacc.w += sigm(fxv.w + pa.w + pb.w) * cv.w;
  }
  #undef PP
  ushort4 ho, co;
  ho.x = f2bf(sigm(ao.x) * tanhf(cacc.x));
  ho.y = f2bf(sigm(ao.y) * tanhf(cacc.y));
  ho.z = f2bf(sigm(ao.z) * tanhf(cacc.z));
  ho.w = f2bf(sigm(ao.w) * tanhf(cacc.w));
  co.x = f2bf(cacc.x); co.y = f2bf(cacc.y); co.z = f2bf(cacc.z); co.w = f2bf(cacc.w);
  *reinterpret_cast<ushort4*>(h + bs*256 + j) = ho;
  *reinterpret_cast<ushort4*>(c_out + bs*256 + j) = co;
}

// ---------------------------------------------------------------------------
__global__ void root_kernel(const uint16_t* __restrict__ h, const int* __restrict__ td_g,
                            float* __restrict__ out_root){
  const int b = blockIdx.x;
  __shared__ int red[256];
  const int* td = td_g + ((long)b*T_ + (T_-1))*S_;
  int m = 0;
  for (int s = threadIdx.x; s < S_; s += 256) m = max(m, td[s]);
  red[threadIdx.x] = m; __syncthreads();
  for (int w = 128; w > 0; w >>= 1){
    if (threadIdx.x < w) red[threadIdx.x] = max(red[threadIdx.x], red[threadIdx.x+w]);
    __syncthreads();
  }
  const int root = red[0];
  out_root[b*256 + threadIdx.x] = bf2f(h[((long)b*512 + root)*256 + threadIdx.x]);
}

// ---------------------------------------------------------------------------
extern "C" void kernel_launch(void* const* d_in, const int* in_sizes, int n_in,
                              void* d_out, int out_size, void* d_ws, size_t ws_size,
                              hipStream_t stream) {
  const int*   input_ids  = (const int*)  d_in[0];
  const int*   tree_ids   = (const int*)  d_in[1];
  const int*   tree_ids_r = (const int*)  d_in[2];
  const int*   tree_ids_l = (const int*)  d_in[3];
  const float* emb        = (const float*)d_in[4];
  const float* W_ioux     = (const float*)d_in[5];
  const float* b_ioux     = (const float*)d_in[6];
  const float* W_f        = (const float*)d_in[9];
  const float* b_f        = (const float*)d_in[10];
  float* out = (float*)d_out;                  // FP32 outputs: h | c | h_root

  // --- workspace layout: fixed ~128 MB + adaptive P chunk ---
  size_t woff = 0;
  auto alloc = [&](size_t bytes)->char*{
    char* p = (char*)d_ws + woff; woff += (bytes + 255) & ~(size_t)255; return p;
  };
  uint16_t* ioufx  = (uint16_t*)alloc((size_t)M_*1024*2);     // 67.1 MB: i|o|u|fx
  uint16_t* hA     = (uint16_t*)alloc((size_t)M_*256*2);      // 16.8 MB (hA,cA,cB contiguous)
  uint16_t* cA     = (uint16_t*)alloc((size_t)M_*256*2);
  uint16_t* cB     = (uint16_t*)alloc((size_t)M_*256*2);
  int* csr_off     = (int*)     alloc((size_t)3*T_*B_*(S_+1)*4);
  int* csr_val     = (int*)     alloc((size_t)3*T_*B_*S_*4);
  uint16_t* UcatT  = (uint16_t*)alloc((size_t)NP_*256*2);     //  1.05 MB
  uint16_t* WallT  = (uint16_t*)alloc((size_t)1024*256*2);    //  0.52 MB
  int CB = 64;                                                // batches per P chunk
  while (CB > 8 && woff + (size_t)CB*S_*NP_*2 > ws_size) CB >>= 1;
  uint16_t* P      = (uint16_t*)alloc((size_t)CB*S_*NP_*2);   // <=134 MB (bf16, blocked)
  uint16_t* embg   = P;                                       // setup-only alias (16.8 MB)

  // --- setup ---
  build_ucatT<<<2048, 256, 0, stream>>>((const float*)d_in[7], (const float*)d_in[8],
      (const float*)d_in[11], (const float*)d_in[12], (const float*)d_in[13], (const float*)d_in[14],
      UcatT);
  build_wallT<<<1024, 256, 0, stream>>>(W_ioux, W_f, WallT);
  gather_embg<<<M_/4, 256, 0, stream>>>(emb, input_ids, embg);
  gemm_pipe<<<(M_/128)*8, 256, 0, stream>>>(embg, WallT, b_ioux, b_f, 768, ioufx, 1024, 8);
  build_csr<<<T_*B_, S_, 0, stream>>>(tree_ids, tree_ids_r, tree_ids_l, csr_off, csr_val);
  zero16<<<12288, 256, 0, stream>>>((uint4*)hA, 3145728L);   // zero hA+cA+cB (50.3MB)

  // --- T steps; h in place, c ping-pong; t=0 degenerate (P=0, c=0) ---
  uint16_t *cc = cA, *cn = cB;
  t0_update<<<M_/4, 256, 0, stream>>>(hA, cn, ioufx, csr_off);
  { uint16_t* tc = cc; cc = cn; cn = tc; }
  for (int t = 1; t < T_; ++t) {
    for (int b0 = 0; b0 < B_; b0 += CB) {
      const int row0 = b0 * S_;
      const int Mc   = CB * S_;
      gemm_step_blk<<<Mc/16, 256, 0, stream>>>(hA + (long)row0*256, UcatT, P);  // (Mc/128)*8
      step_update<<<CB*128, 256, 0, stream>>>(hA, cc, cn, P, ioufx,
                                              csr_off, csr_val, tree_ids_r, tree_ids_l,
                                              t, row0);
    }
    uint16_t* tc = cc; cc = cn; cn = tc;
  }
  // 12 swaps total -> cc == cA at exit

  // --- outputs (fp32): h | c | h_root ---
  bf16_to_f32<<<8192, 256, 0, stream>>>(hA, out, (long)M_*256);                 // h
  bf16_to_f32<<<8192, 256, 0, stream>>>(cc, out + (long)M_*256, (long)M_*256);  // c
  root_kernel<<<B_, 256, 0, stream>>>(hA, tree_ids, out + 2L*M_*256);           // h_root
}

// Round 16
// 1126.884 us; speedup vs baseline: 1.3579x; 1.3579x over previous
//
#include <hip/hip_runtime.h>
#include <stdint.h>

#define B_ 64
#define S_ 512
#define T_ 12
#define M_ (B_*S_)      // 32768 rows
#define NP_ 2048        // width of per-step projection P

typedef __attribute__((ext_vector_type(8))) short bf16x8;   // 8 bf16 = 4 VGPR
typedef __attribute__((ext_vector_type(4))) float f32x4;    // MFMA accumulator

__device__ __forceinline__ uint16_t f2bf(float f){
  union { float f; uint32_t u; } x; x.f = f;
  uint32_t r = x.u + 0x7FFFu + ((x.u >> 16) & 1u);   // RTNE
  return (uint16_t)(r >> 16);
}
__device__ __forceinline__ float bf2f(uint16_t u){
  union { float f; uint32_t u; } x; x.u = ((uint32_t)u) << 16; return x.f;
}
__device__ __forceinline__ float sigm(float x){ return 1.0f/(1.0f + expf(-x)); }
__device__ __forceinline__ float4 bf4(const uint16_t* p){
  const ushort4 v = *reinterpret_cast<const ushort4*>(p);
  return make_float4(bf2f(v.x), bf2f(v.y), bf2f(v.z), bf2f(v.w));
}

// async global->LDS, 16B per lane; LDS dest = wave-uniform base + lane*16
__device__ __forceinline__ void gload16(const uint16_t* g, uint16_t* l){
  __builtin_amdgcn_global_load_lds(
      (const __attribute__((address_space(1))) uint32_t*)g,
      (__attribute__((address_space(3))) uint32_t*)l, 16, 0, 0);
}

// ---------------------------------------------------------------------------
__global__ void zero16(uint4* __restrict__ p, long n16){
  const long i = (long)blockIdx.x * 256 + threadIdx.x;
  if (i < n16) p[i] = make_uint4(0,0,0,0);
}
__global__ void bf16_to_f32(const uint16_t* __restrict__ src, float* __restrict__ dst, long n){
  const long i = ((long)blockIdx.x * 256 + threadIdx.x) * 4;
  if (i + 3 < n) {
    const float4 o = bf4(src + i);
    *reinterpret_cast<float4*>(dst + i) = o;
  }
}

// ---------------------------------------------------------------------------
// UcatT[2048][256] bf16, UcatT[n][k] = [U_iou_r | U_iou_l | U_f0+U_f1 | U_f2+U_f3][k][n]
__global__ void build_ucatT(const float* __restrict__ Ur, const float* __restrict__ Ul,
                            const float* __restrict__ f0, const float* __restrict__ f1,
                            const float* __restrict__ f2, const float* __restrict__ f3,
                            uint16_t* __restrict__ UcatT){
  const int idx = blockIdx.x * 256 + threadIdx.x;   // 2048*256 total
  const int n = idx >> 8, k = idx & 255;
  float v;
  if (n < 768)        v = Ur[k*768 + n];
  else if (n < 1536)  v = Ul[k*768 + (n-768)];
  else if (n < 1792) { int j = n-1536; v = f0[k*256+j] + f1[k*256+j]; }
  else               { int j = n-1792; v = f2[k*256+j] + f3[k*256+j]; }
  UcatT[(long)n*256 + k] = f2bf(v);
}

// WallT[1024][256] bf16 = [W_ioux | W_f]^T   (grid = 1024, 256 threads)
__global__ void build_wallT(const float* __restrict__ Wioux, const float* __restrict__ Wf,
                            uint16_t* __restrict__ WT){
  const int idx = blockIdx.x * 256 + threadIdx.x;   // 1024*256 total
  const int n = idx >> 8, k = idx & 255;
  const float v = (n < 768) ? Wioux[(long)k*768 + n] : Wf[(long)k*256 + (n-768)];
  WT[(long)n*256 + k] = f2bf(v);
}

// embg[M][256] bf16 = emb[input_ids[r]][k]  (gather + convert; 1 wave/row)
__global__ void gather_embg(const float* __restrict__ emb, const int* __restrict__ ids,
                            uint16_t* __restrict__ out){
  const int wave = threadIdx.x >> 6, lane = threadIdx.x & 63;
  const long row = (long)blockIdx.x*4 + wave;
  const long rid = (long)ids[row];
  const float4 v = *reinterpret_cast<const float4*>(emb + rid*256 + lane*4);
  ushort4 o; o.x=f2bf(v.x); o.y=f2bf(v.y); o.z=f2bf(v.z); o.w=f2bf(v.w);
  *reinterpret_cast<ushort4*>(out + row*256 + lane*4) = o;
}

// ---------------------------------------------------------------------------
// Unified MFMA GEMM (bf16 A, K=256): 2-buffer counted-vmcnt pipeline in 32 KB
// LDS, XOR seg-swizzle on global source AND ds_read, XCD-pinned m-tiles,
// coalesced C-store via LDS restage. grid=(M/128)*NT.
__global__ __launch_bounds__(256)
void gemm_pipe(const uint16_t* __restrict__ A, const uint16_t* __restrict__ BT,
               const float* __restrict__ bias, const float* __restrict__ bias2, int split,
               uint16_t* __restrict__ C, int N, int NT)
{
  __shared__ __align__(16) uint16_t smem[16384];   // A0|A1|B0|B1 (4096 u16 each) = 32 KB
  const int tid = threadIdx.x, lane = tid & 63, wave = tid >> 6;
  const int wr = wave >> 1, wc = wave & 1;
  const int id = blockIdx.x, rx = id & 7, q = id >> 3;
  const int mt = rx + 8*(q / NT);
  const int nt = q % NT;
  const long m0 = (long)mt * 128;
  const int  n0 = nt * 128;

  const int rl0 = wave*32 + (lane >> 2);
  const int rl1 = rl0 + 16;
  const int sg0 = (lane & 3) ^ ((rl0 >> 1) & 3);
  const int sg1 = (lane & 3) ^ ((rl1 >> 1) & 3);
  const uint16_t* ga0 = A + (m0 + rl0)*256 + sg0*8;
  const uint16_t* ga1 = A + (m0 + rl1)*256 + sg1*8;
  const uint16_t* gb0 = BT + (long)(n0 + rl0)*256 + sg0*8;
  const uint16_t* gb1 = BT + (long)(n0 + rl1)*256 + sg1*8;

  f32x4 acc[4][4];
  #pragma unroll
  for (int i=0;i<4;i++)
    #pragma unroll
    for (int j=0;j<4;j++) acc[i][j] = (f32x4){0.f,0.f,0.f,0.f};

  const int l15 = lane & 15, lseg = lane >> 4;
  int aoff[4], boff[4];
  #pragma unroll
  for (int i=0;i<4;i++){ const int m = wr*64 + i*16 + l15; aoff[i] = m*32 + ((lseg ^ ((m>>1)&3))<<3); }
  #pragma unroll
  for (int j=0;j<4;j++){ const int n = wc*64 + j*16 + l15; boff[j] = n*32 + ((lseg ^ ((n>>1)&3))<<3); }

  #define STAGE(tile, buf) {                                   \
    const int ks_ = (tile)*32;                                 \
    uint16_t* a_ = &smem[(buf)*4096 + wave*1024];              \
    uint16_t* b_ = &smem[8192 + (buf)*4096 + wave*1024];       \
    gload16(ga0 + ks_, a_); gload16(ga1 + ks_, a_ + 512);      \
    gload16(gb0 + ks_, b_); gload16(gb1 + ks_, b_ + 512);      \
  }

  STAGE(0, 0)
  STAGE(1, 1)

  #pragma unroll
  for (int tt = 0; tt < 8; ++tt) {
    if (tt < 7) asm volatile("s_waitcnt vmcnt(4)" ::: "memory");
    else        asm volatile("s_waitcnt vmcnt(0)" ::: "memory");
    __builtin_amdgcn_s_barrier();
    const int cb = tt & 1;
    bf16x8 af[4], bfv[4];
    #pragma unroll
    for (int i=0;i<4;i++) af[i]  = *reinterpret_cast<const bf16x8*>(&smem[cb*4096 + aoff[i]]);
    #pragma unroll
    for (int j=0;j<4;j++) bfv[j] = *reinterpret_cast<const bf16x8*>(&smem[8192 + cb*4096 + boff[j]]);
    __builtin_amdgcn_s_setprio(1);
    #pragma unroll
    for (int i=0;i<4;i++)
      #pragma unroll
      for (int j=0;j<4;j++)
        acc[i][j] = __builtin_amdgcn_mfma_f32_16x16x32_bf16(af[i], bfv[j], acc[i][j], 0, 0, 0);
    __builtin_amdgcn_s_setprio(0);
    if (tt < 6) {
      __builtin_amdgcn_s_barrier();
      STAGE(tt + 2, cb)
    }
  }
  #undef STAGE

  __syncthreads();
  const int rquad = lane >> 4;
  const int rowq = tid >> 4;
  const int cseg = tid & 15;
  float bv[4];
  #pragma unroll
  for (int j=0;j<4;j++){
    const int col = n0 + wc*64 + j*16 + l15;
    bv[j] = bias ? ((col < split) ? bias[col] : bias2[col - split]) : 0.0f;
  }
  #pragma unroll
  for (int half = 0; half < 2; ++half) {
    if (wr == half) {
      #pragma unroll
      for (int i=0;i<4;i++)
        #pragma unroll
        for (int j=0;j<4;j++)
          #pragma unroll
          for (int r=0;r<4;r++)
            smem[(i*16 + rquad*4 + r)*136 + wc*64 + j*16 + l15] = f2bf(acc[i][j][r] + bv[j]);
    }
    __syncthreads();
    #pragma unroll
    for (int it=0; it<4; ++it) {
      const int r2 = it*16 + rowq;
      const uint4 v = *reinterpret_cast<const uint4*>(&smem[r2*136 + cseg*8]);
      *reinterpret_cast<uint4*>(C + (m0 + half*64 + r2)*N + n0 + cseg*8) = v;
    }
    __syncthreads();
  }
}

// ---------------------------------------------------------------------------
// Deterministic CSR inversion, chunked-histogram rank (no serial section).
// One block per (t,b), 512 threads; chunk q = wave = s>>6.
__global__ void build_csr(const int* __restrict__ td_g, const int* __restrict__ tr_g,
                          const int* __restrict__ tl_g,
                          int* __restrict__ csr_off, int* __restrict__ csr_val){
  const int t = blockIdx.x >> 6;
  const int b = blockIdx.x & 63;
  __shared__ int ids[S_];
  __shared__ int cnt[S_];
  __shared__ int off[S_];
  __shared__ int chc[8][S_];                      // per-chunk histogram
  const int s = threadIdx.x;                      // 512 threads
  const int q = s >> 6;                           // chunk = wave index
  const int* srcs[3] = {td_g, tr_g, tl_g};
  for (int arr = 0; arr < 3; ++arr) {
    const int myid = srcs[arr][((long)b*T_ + t)*S_ + s];   // layout [B][T][S]
    ids[s] = myid;
    cnt[s] = 0;
    #pragma unroll
    for (int qq=0; qq<8; qq++) chc[qq][s] = 0;
    __syncthreads();
    atomicAdd(&cnt[myid], 1);
    atomicAdd(&chc[q][myid], 1);
    __syncthreads();
    // stable rank: earlier chunks' counts + in-chunk scan (<=63 iters)
    int rank = 0;
    for (int qq = 0; qq < q; ++qq) rank += chc[qq][myid];
    for (int i = q*64; i < s; ++i) rank += (ids[i] == myid) ? 1 : 0;
    // inclusive scan of cnt -> off
    off[s] = cnt[s];
    __syncthreads();
    for (int w = 1; w < S_; w <<= 1){
      const int v = (s >= w) ? off[s-w] : 0;
      __syncthreads();
      off[s] += v;
      __syncthreads();
    }
    const long base = (((long)arr*T_ + t)*B_ + b);
    int* offs = csr_off + base*(S_+1);
    int* vals = csr_val + base*S_;
    offs[s] = off[s] - cnt[s];                    // exclusive
    if (s == S_-1) offs[S_] = off[s];
    vals[(off[myid] - cnt[myid]) + rank] = s;     // stable: ascending source order
    __syncthreads();
  }
}

// ---------------------------------------------------------------------------
// t=0 special case: h=c=0 -> P=0 and f*c terms vanish. Masked rows:
// c = sigm(i)*tanh(u); h = sigm(o)*tanh(c). Unmasked: buffers stay zero.
__global__ __launch_bounds__(256)
void t0_update(uint16_t* __restrict__ h, uint16_t* __restrict__ c_out,
               const uint16_t* __restrict__ ioufx, const int* __restrict__ csr_off)
{
  const int wave = threadIdx.x >> 6, lane = threadIdx.x & 63;
  const long bs = (long)blockIdx.x*4 + wave;
  const int b = (int)(bs >> 9), s = (int)(bs & 511);
  const int j = lane * 4;
  const int* off_td = csr_off + (long)b*(S_+1);        // arr=0, t=0
  if (s == 0 || off_td[s+1] <= off_td[s]) return;      // unmasked: stay zero
  const long ib = bs*1024;
  const float4 ai = bf4(ioufx + ib + j);
  const float4 ao = bf4(ioufx + ib + 256 + j);
  const float4 au = bf4(ioufx + ib + 512 + j);
  float4 cacc;
  cacc.x = sigm(ai.x)*tanhf(au.x); cacc.y = sigm(ai.y)*tanhf(au.y);
  cacc.z = sigm(ai.z)*tanhf(au.z); cacc.w = sigm(ai.w)*tanhf(au.w);
  ushort4 ho, co;
  ho.x = f2bf(sigm(ao.x)*tanhf(cacc.x)); ho.y = f2bf(sigm(ao.y)*tanhf(cacc.y));
  ho.z = f2bf(sigm(ao.z)*tanhf(cacc.z)); ho.w = f2bf(sigm(ao.w)*tanhf(cacc.w));
  co.x = f2bf(cacc.x); co.y = f2bf(cacc.y); co.z = f2bf(cacc.z); co.w = f2bf(cacc.w);
  *reinterpret_cast<ushort4*>(h + bs*256 + j) = ho;
  *reinterpret_cast<ushort4*>(c_out + bs*256 + j) = co;
}

// ---------------------------------------------------------------------------
// Per-step destination-side update. 1 wave per row, lane owns 4 channels.
// XCD-pinned per batch-element (b's 2MB P-window stays in one L2).
// h updated IN PLACE; c ping-pongs. grid = CB*128.
__global__ __launch_bounds__(256)
void step_update(uint16_t* __restrict__ h,
                 const uint16_t* __restrict__ c_in, uint16_t* __restrict__ c_out,
                 const uint16_t* __restrict__ P,      // [Mc][2048] bf16, chunk-local rows
                 const uint16_t* __restrict__ ioufx,  // [M][1024] bf16: i|o|u|fx
                 const int* __restrict__ csr_off, const int* __restrict__ csr_val,
                 const int* __restrict__ tr_g, const int* __restrict__ tl_g,
                 int t, int row0)
{
  const int wave = threadIdx.x >> 6, lane = threadIdx.x & 63;
  const int id = blockIdx.x, rx = id & 7, q = id >> 3;
  const int b_local = rx + 8*(q >> 7);                   // [0,CB)
  const int rg = q & 127;                                // [0,128)
  const long bs = (long)row0 + b_local*512 + rg*4 + wave;
  const int b = (int)(bs >> 9), s = (int)(bs & 511);
  const int j = lane * 4;             // channel group

  const int* off_td = csr_off + (((long)0*T_ + t)*B_ + b)*(S_+1);
  const int td0 = off_td[s], td1 = off_td[s+1];
  const bool masked = (s != 0) && (td1 > td0);
  if (!masked) {
    *reinterpret_cast<ushort4*>(c_out + bs*256 + j) =
        *reinterpret_cast<const ushort4*>(c_in + bs*256 + j);
    return;                            // h unchanged (in place)
  }
  const int* off_tr = csr_off + (((long)1*T_ + t)*B_ + b)*(S_+1);
  const int* off_tl = csr_off + (((long)2*T_ + t)*B_ + b)*(S_+1);
  const int* val_td = csr_val + (((long)0*T_ + t)*B_ + b)*S_;
  const int* val_tr = csr_val + (((long)1*T_ + t)*B_ + b)*S_;
  const int* val_tl = csr_val + (((long)2*T_ + t)*B_ + b)*S_;

  const long lbase = (long)(b<<9) - row0;             // chunk-local row base for P

  const long ib = bs*1024;
  float4 ai = bf4(ioufx + ib + j);
  float4 ao = bf4(ioufx + ib + 256 + j);
  float4 au = bf4(ioufx + ib + 512 + j);
  for (int p = off_tr[s]; p < off_tr[s+1]; ++p) {     // sources s' with tr[s']==s
    const long pr = (lbase + val_tr[p]) * NP_;
    const float4 x = bf4(P + pr + j), y = bf4(P + pr + 256 + j), z = bf4(P + pr + 512 + j);
    ai.x+=x.x; ai.y+=x.y; ai.z+=x.z; ai.w+=x.w;
    ao.x+=y.x; ao.y+=y.y; ao.z+=y.z; ao.w+=y.w;
    au.x+=z.x; au.y+=z.y; au.z+=z.z; au.w+=z.w;
  }
  for (int p = off_tl[s]; p < off_tl[s+1]; ++p) {     // sources s' with tl[s']==s
    const long pr = (lbase + val_tl[p]) * NP_;
    const float4 x = bf4(P + pr + 768 + j), y = bf4(P + pr + 1024 + j), z = bf4(P + pr + 1280 + j);
    ai.x+=x.x; ai.y+=x.y; ai.z+=x.z; ai.w+=x.w;
    ao.x+=y.x; ao.y+=y.y; ao.z+=y.z; ao.w+=y.w;
    au.x+=z.x; au.y+=z.y; au.z+=z.z; au.w+=z.w;
  }
  float4 cacc;
  cacc.x = sigm(ai.x)*tanhf(au.x); cacc.y = sigm(ai.y)*tanhf(au.y);
  cacc.z = sigm(ai.z)*tanhf(au.z); cacc.w = sigm(ai.w)*tanhf(au.w);
  const float4 fxv = bf4(ioufx + ib + 768 + j);       // f_x at the DESTINATION row
  const int* trrow = tr_g + ((long)b*T_ + t)*S_;
  const int* tlrow = tl_g + ((long)b*T_ + t)*S_;
  for (int p = td0; p < td1; ++p) {                   // children s' with td[s']==s
    const int sp = val_td[p];
    const long prr = (lbase + trrow[sp]) * NP_ + 1536;  // gather P_f01 at tr[s']
    const long prl = (lbase + tlrow[sp]) * NP_ + 1792;  // gather P_f23 at tl[s']
    const float4 pa = bf4(P + prr + j), pb = bf4(P + prl + j);
    const float4 cv = bf4(c_in + ((long)(b<<9) + sp)*256 + j);
    cacc.x += sigm(fxv.x + pa.x + pb.x) * cv.x;
    cacc.y += sigm(fxv.y + pa.y + pb.y) * cv.y;
    cacc.z += sigm(fxv.z + pa.z + pb.z) * cv.z;
    cacc.w += sigm(fxv.w + pa.w + pb.w) * cv.w;
  }
  ushort4 ho, co;
  ho.x = f2bf(sigm(ao.x) * tanhf(cacc.x));
  ho.y = f2bf(sigm(ao.y) * tanhf(cacc.y));
  ho.z = f2bf(sigm(ao.z) * tanhf(cacc.z));
  ho.w = f2bf(sigm(ao.w) * tanhf(cacc.w));
  co.x = f2bf(cacc.x); co.y = f2bf(cacc.y); co.z = f2bf(cacc.z); co.w = f2bf(cacc.w);
  *reinterpret_cast<ushort4*>(h + bs*256 + j) = ho;
  *reinterpret_cast<ushort4*>(c_out + bs*256 + j) = co;
}

// ---------------------------------------------------------------------------
__global__ void root_kernel(const uint16_t* __restrict__ h, const int* __restrict__ td_g,
                            float* __restrict__ out_root){
  const int b = blockIdx.x;
  __shared__ int red[256];
  const int* td = td_g + ((long)b*T_ + (T_-1))*S_;
  int m = 0;
  for (int s = threadIdx.x; s < S_; s += 256) m = max(m, td[s]);
  red[threadIdx.x] = m; __syncthreads();
  for (int w = 128; w > 0; w >>= 1){
    if (threadIdx.x < w) red[threadIdx.x] = max(red[threadIdx.x], red[threadIdx.x+w]);
    __syncthreads();
  }
  const int root = red[0];
  out_root[b*256 + threadIdx.x] = bf2f(h[((long)b*512 + root)*256 + threadIdx.x]);
}

// ---------------------------------------------------------------------------
extern "C" void kernel_launch(void* const* d_in, const int* in_sizes, int n_in,
                              void* d_out, int out_size, void* d_ws, size_t ws_size,
                              hipStream_t stream) {
  const int*   input_ids  = (const int*)  d_in[0];
  const int*   tree_ids   = (const int*)  d_in[1];
  const int*   tree_ids_r = (const int*)  d_in[2];
  const int*   tree_ids_l = (const int*)  d_in[3];
  const float* emb        = (const float*)d_in[4];
  const float* W_ioux     = (const float*)d_in[5];
  const float* b_ioux     = (const float*)d_in[6];
  const float* W_f        = (const float*)d_in[9];
  const float* b_f        = (const float*)d_in[10];
  float* out = (float*)d_out;                  // FP32 outputs: h | c | h_root

  // --- workspace layout: fixed ~128 MB + adaptive P chunk ---
  size_t woff = 0;
  auto alloc = [&](size_t bytes)->char*{
    char* p = (char*)d_ws + woff; woff += (bytes + 255) & ~(size_t)255; return p;
  };
  uint16_t* ioufx  = (uint16_t*)alloc((size_t)M_*1024*2);     // 67.1 MB: i|o|u|fx
  uint16_t* hA     = (uint16_t*)alloc((size_t)M_*256*2);      // 16.8 MB (hA,cA,cB contiguous)
  uint16_t* cA     = (uint16_t*)alloc((size_t)M_*256*2);
  uint16_t* cB     = (uint16_t*)alloc((size_t)M_*256*2);
  int* csr_off     = (int*)     alloc((size_t)3*T_*B_*(S_+1)*4);
  int* csr_val     = (int*)     alloc((size_t)3*T_*B_*S_*4);
  uint16_t* UcatT  = (uint16_t*)alloc((size_t)NP_*256*2);     //  1.05 MB
  uint16_t* WallT  = (uint16_t*)alloc((size_t)1024*256*2);    //  0.52 MB
  int CB = 64;                                                // batches per P chunk
  while (CB > 8 && woff + (size_t)CB*S_*NP_*2 > ws_size) CB >>= 1;
  uint16_t* P      = (uint16_t*)alloc((size_t)CB*S_*NP_*2);   // <=134 MB (bf16)
  uint16_t* embg   = P;                                       // setup-only alias (16.8 MB)

  // --- setup ---
  build_ucatT<<<2048, 256, 0, stream>>>((const float*)d_in[7], (const float*)d_in[8],
      (const float*)d_in[11], (const float*)d_in[12], (const float*)d_in[13], (const float*)d_in[14],
      UcatT);
  build_wallT<<<1024, 256, 0, stream>>>(W_ioux, W_f, WallT);
  gather_embg<<<M_/4, 256, 0, stream>>>(emb, input_ids, embg);
  gemm_pipe<<<(M_/128)*8, 256, 0, stream>>>(embg, WallT, b_ioux, b_f, 768, ioufx, 1024, 8);
  build_csr<<<T_*B_, S_, 0, stream>>>(tree_ids, tree_ids_r, tree_ids_l, csr_off, csr_val);
  zero16<<<12288, 256, 0, stream>>>((uint4*)hA, 3145728L);   // zero hA+cA+cB (50.3MB)

  // --- T steps; h in place, c ping-pong; t=0 degenerate (P=0, c=0) ---
  uint16_t *cc = cA, *cn = cB;
  t0_update<<<M_/4, 256, 0, stream>>>(hA, cn, ioufx, csr_off);
  { uint16_t* tc = cc; cc = cn; cn = tc; }
  for (int t = 1; t < T_; ++t) {
    for (int b0 = 0; b0 < B_; b0 += CB) {
      const int row0 = b0 * S_;
      const int Mc   = CB * S_;
      gemm_pipe<<<(Mc/128)*16, 256, 0, stream>>>(hA + (long)row0*256, UcatT,
                                                 nullptr, nullptr, 0, P, NP_, 16);
      step_update<<<CB*128, 256, 0, stream>>>(hA, cc, cn, P, ioufx,
                                              csr_off, csr_val, tree_ids_r, tree_ids_l,
                                              t, row0);
    }
    uint16_t* tc = cc; cc = cn; cn = tc;
  }
  // 12 swaps total -> cc == cA at exit

  // --- outputs (fp32): h | c | h_root ---
  bf16_to_f32<<<8192, 256, 0, stream>>>(hA, out, (long)M_*256);                 // h
  bf16_to_f32<<<8192, 256, 0, stream>>>(cc, out + (long)M_*256, (long)M_*256);  // c
  root_kernel<<<B_, 256, 0, stream>>>(hA, tree_ids, out + 2L*M_*256);           // h_root
}

// Round 17
// 1114.176 us; speedup vs baseline: 1.3734x; 1.0114x over previous
//
#include <hip/hip_runtime.h>
#include <stdint.h>

#define B_ 64
#define S_ 512
#define T_ 12
#define M_ (B_*S_)      // 32768 rows
#define NP_ 2048        // width of per-step projection P

typedef __attribute__((ext_vector_type(8))) short bf16x8;   // 8 bf16 = 4 VGPR
typedef __attribute__((ext_vector_type(4))) float f32x4;    // MFMA accumulator

__device__ __forceinline__ uint16_t f2bf(float f){
  union { float f; uint32_t u; } x; x.f = f;
  uint32_t r = x.u + 0x7FFFu + ((x.u >> 16) & 1u);   // RTNE
  return (uint16_t)(r >> 16);
}
__device__ __forceinline__ float bf2f(uint16_t u){
  union { float f; uint32_t u; } x; x.u = ((uint32_t)u) << 16; return x.f;
}
__device__ __forceinline__ float sigm(float x){ return 1.0f/(1.0f + expf(-x)); }
__device__ __forceinline__ float4 bf4(const uint16_t* p){
  const ushort4 v = *reinterpret_cast<const ushort4*>(p);
  return make_float4(bf2f(v.x), bf2f(v.y), bf2f(v.z), bf2f(v.w));
}

// async global->LDS, 16B per lane; LDS dest = wave-uniform base + lane*16
__device__ __forceinline__ void gload16(const uint16_t* g, uint16_t* l){
  __builtin_amdgcn_global_load_lds(
      (const __attribute__((address_space(1))) uint32_t*)g,
      (__attribute__((address_space(3))) uint32_t*)l, 16, 0, 0);
}

// ---------------------------------------------------------------------------
__global__ void zero16(uint4* __restrict__ p, long n16){
  const long i = (long)blockIdx.x * 256 + threadIdx.x;
  if (i < n16) p[i] = make_uint4(0,0,0,0);
}
__global__ void bf16_to_f32(const uint16_t* __restrict__ src, float* __restrict__ dst, long n){
  const long i = ((long)blockIdx.x * 256 + threadIdx.x) * 4;
  if (i + 3 < n) {
    const float4 o = bf4(src + i);
    *reinterpret_cast<float4*>(dst + i) = o;
  }
}

// ---------------------------------------------------------------------------
// UcatT[2048][256] bf16, UcatT[n][k] = [U_iou_r | U_iou_l | U_f0+U_f1 | U_f2+U_f3][k][n]
__global__ void build_ucatT(const float* __restrict__ Ur, const float* __restrict__ Ul,
                            const float* __restrict__ f0, const float* __restrict__ f1,
                            const float* __restrict__ f2, const float* __restrict__ f3,
                            uint16_t* __restrict__ UcatT){
  const int idx = blockIdx.x * 256 + threadIdx.x;   // 2048*256 total
  const int n = idx >> 8, k = idx & 255;
  float v;
  if (n < 768)        v = Ur[k*768 + n];
  else if (n < 1536)  v = Ul[k*768 + (n-768)];
  else if (n < 1792) { int j = n-1536; v = f0[k*256+j] + f1[k*256+j]; }
  else               { int j = n-1792; v = f2[k*256+j] + f3[k*256+j]; }
  UcatT[(long)n*256 + k] = f2bf(v);
}

// WallT[1024][256] bf16 = [W_ioux | W_f]^T   (grid = 1024, 256 threads)
__global__ void build_wallT(const float* __restrict__ Wioux, const float* __restrict__ Wf,
                            uint16_t* __restrict__ WT){
  const int idx = blockIdx.x * 256 + threadIdx.x;   // 1024*256 total
  const int n = idx >> 8, k = idx & 255;
  const float v = (n < 768) ? Wioux[(long)k*768 + n] : Wf[(long)k*256 + (n-768)];
  WT[(long)n*256 + k] = f2bf(v);
}

// embg[M][256] bf16 = emb[input_ids[r]][k]  (gather + convert; 1 wave/row)
__global__ void gather_embg(const float* __restrict__ emb, const int* __restrict__ ids,
                            uint16_t* __restrict__ out){
  const int wave = threadIdx.x >> 6, lane = threadIdx.x & 63;
  const long row = (long)blockIdx.x*4 + wave;
  const long rid = (long)ids[row];
  const float4 v = *reinterpret_cast<const float4*>(emb + rid*256 + lane*4);
  ushort4 o; o.x=f2bf(v.x); o.y=f2bf(v.y); o.z=f2bf(v.z); o.w=f2bf(v.w);
  *reinterpret_cast<ushort4*>(out + row*256 + lane*4) = o;
}

// ---------------------------------------------------------------------------
// Unified MFMA GEMM (bf16 A, K=256): 2-buffer counted-vmcnt pipeline in 32 KB
// LDS, XOR seg-swizzle on global source AND ds_read, XCD-pinned m-tiles,
// coalesced C-store via LDS restage. STAGE issued BEFORE the MFMA cluster
// (reads certified by lgkmcnt(0)+barrier) for ~320cy extra load coverage.
// grid=(M/128)*NT.
__global__ __launch_bounds__(256)
void gemm_pipe(const uint16_t* __restrict__ A, const uint16_t* __restrict__ BT,
               const float* __restrict__ bias, const float* __restrict__ bias2, int split,
               uint16_t* __restrict__ C, int N, int NT)
{
  __shared__ __align__(16) uint16_t smem[16384];   // A0|A1|B0|B1 (4096 u16 each) = 32 KB
  const int tid = threadIdx.x, lane = tid & 63, wave = tid >> 6;
  const int wr = wave >> 1, wc = wave & 1;
  const int id = blockIdx.x, rx = id & 7, q = id >> 3;
  const int mt = rx + 8*(q / NT);
  const int nt = q % NT;
  const long m0 = (long)mt * 128;
  const int  n0 = nt * 128;

  const int rl0 = wave*32 + (lane >> 2);
  const int rl1 = rl0 + 16;
  const int sg0 = (lane & 3) ^ ((rl0 >> 1) & 3);
  const int sg1 = (lane & 3) ^ ((rl1 >> 1) & 3);
  const uint16_t* ga0 = A + (m0 + rl0)*256 + sg0*8;
  const uint16_t* ga1 = A + (m0 + rl1)*256 + sg1*8;
  const uint16_t* gb0 = BT + (long)(n0 + rl0)*256 + sg0*8;
  const uint16_t* gb1 = BT + (long)(n0 + rl1)*256 + sg1*8;

  f32x4 acc[4][4];
  #pragma unroll
  for (int i=0;i<4;i++)
    #pragma unroll
    for (int j=0;j<4;j++) acc[i][j] = (f32x4){0.f,0.f,0.f,0.f};

  const int l15 = lane & 15, lseg = lane >> 4;
  int aoff[4], boff[4];
  #pragma unroll
  for (int i=0;i<4;i++){ const int m = wr*64 + i*16 + l15; aoff[i] = m*32 + ((lseg ^ ((m>>1)&3))<<3); }
  #pragma unroll
  for (int j=0;j<4;j++){ const int n = wc*64 + j*16 + l15; boff[j] = n*32 + ((lseg ^ ((n>>1)&3))<<3); }

  #define STAGE(tile, buf) {                                   \
    const int ks_ = (tile)*32;                                 \
    uint16_t* a_ = &smem[(buf)*4096 + wave*1024];              \
    uint16_t* b_ = &smem[8192 + (buf)*4096 + wave*1024];       \
    gload16(ga0 + ks_, a_); gload16(ga1 + ks_, a_ + 512);      \
    gload16(gb0 + ks_, b_); gload16(gb1 + ks_, b_ + 512);      \
  }

  STAGE(0, 0)
  STAGE(1, 1)

  #pragma unroll
  for (int tt = 0; tt < 8; ++tt) {
    if (tt < 7) asm volatile("s_waitcnt vmcnt(4)" ::: "memory");
    else        asm volatile("s_waitcnt vmcnt(0)" ::: "memory");
    __builtin_amdgcn_s_barrier();            // tile tt visible to all waves
    const int cb = tt & 1;
    bf16x8 af[4], bfv[4];
    #pragma unroll
    for (int i=0;i<4;i++) af[i]  = *reinterpret_cast<const bf16x8*>(&smem[cb*4096 + aoff[i]]);
    #pragma unroll
    for (int j=0;j<4;j++) bfv[j] = *reinterpret_cast<const bf16x8*>(&smem[8192 + cb*4096 + boff[j]]);
    if (tt < 6) {
      asm volatile("s_waitcnt lgkmcnt(0)" ::: "memory");   // this wave's reads -> regs
      __builtin_amdgcn_sched_barrier(0);                   // pin order (rule #18)
      __builtin_amdgcn_s_barrier();                        // ALL waves done reading buf cb
      STAGE(tt + 2, cb)                                    // overwrite early; lands in ~2 iters
    }
    __builtin_amdgcn_s_setprio(1);
    #pragma unroll
    for (int i=0;i<4;i++)
      #pragma unroll
      for (int j=0;j<4;j++)
        acc[i][j] = __builtin_amdgcn_mfma_f32_16x16x32_bf16(af[i], bfv[j], acc[i][j], 0, 0, 0);
    __builtin_amdgcn_s_setprio(0);
  }
  #undef STAGE

  __syncthreads();
  const int rquad = lane >> 4;
  const int rowq = tid >> 4;
  const int cseg = tid & 15;
  float bv[4];
  #pragma unroll
  for (int j=0;j<4;j++){
    const int col = n0 + wc*64 + j*16 + l15;
    bv[j] = bias ? ((col < split) ? bias[col] : bias2[col - split]) : 0.0f;
  }
  #pragma unroll
  for (int half = 0; half < 2; ++half) {
    if (wr == half) {
      #pragma unroll
      for (int i=0;i<4;i++)
        #pragma unroll
        for (int j=0;j<4;j++)
          #pragma unroll
          for (int r=0;r<4;r++)
            smem[(i*16 + rquad*4 + r)*136 + wc*64 + j*16 + l15] = f2bf(acc[i][j][r] + bv[j]);
    }
    __syncthreads();
    #pragma unroll
    for (int it=0; it<4; ++it) {
      const int r2 = it*16 + rowq;
      const uint4 v = *reinterpret_cast<const uint4*>(&smem[r2*136 + cseg*8]);
      *reinterpret_cast<uint4*>(C + (m0 + half*64 + r2)*N + n0 + cseg*8) = v;
    }
    __syncthreads();
  }
}

// ---------------------------------------------------------------------------
// Deterministic CSR inversion, chunked-histogram rank (no serial section).
// One block per (t,b), 512 threads; chunk q = wave = s>>6.
__global__ void build_csr(const int* __restrict__ td_g, const int* __restrict__ tr_g,
                          const int* __restrict__ tl_g,
                          int* __restrict__ csr_off, int* __restrict__ csr_val){
  const int t = blockIdx.x >> 6;
  const int b = blockIdx.x & 63;
  __shared__ int ids[S_];
  __shared__ int cnt[S_];
  __shared__ int off[S_];
  __shared__ int chc[8][S_];                      // per-chunk histogram
  const int s = threadIdx.x;                      // 512 threads
  const int q = s >> 6;                           // chunk = wave index
  const int* srcs[3] = {td_g, tr_g, tl_g};
  for (int arr = 0; arr < 3; ++arr) {
    const int myid = srcs[arr][((long)b*T_ + t)*S_ + s];   // layout [B][T][S]
    ids[s] = myid;
    cnt[s] = 0;
    #pragma unroll
    for (int qq=0; qq<8; qq++) chc[qq][s] = 0;
    __syncthreads();
    atomicAdd(&cnt[myid], 1);
    atomicAdd(&chc[q][myid], 1);
    __syncthreads();
    // stable rank: earlier chunks' counts + in-chunk scan (<=63 iters)
    int rank = 0;
    for (int qq = 0; qq < q; ++qq) rank += chc[qq][myid];
    for (int i = q*64; i < s; ++i) rank += (ids[i] == myid) ? 1 : 0;
    // inclusive scan of cnt -> off
    off[s] = cnt[s];
    __syncthreads();
    for (int w = 1; w < S_; w <<= 1){
      const int v = (s >= w) ? off[s-w] : 0;
      __syncthreads();
      off[s] += v;
      __syncthreads();
    }
    const long base = (((long)arr*T_ + t)*B_ + b);
    int* offs = csr_off + base*(S_+1);
    int* vals = csr_val + base*S_;
    offs[s] = off[s] - cnt[s];                    // exclusive
    if (s == S_-1) offs[S_] = off[s];
    vals[(off[myid] - cnt[myid]) + rank] = s;     // stable: ascending source order
    __syncthreads();
  }
}

// ---------------------------------------------------------------------------
// t=0 special case: h=c=0 -> P=0 and f*c terms vanish. Masked rows:
// c = sigm(i)*tanh(u); h = sigm(o)*tanh(c). Unmasked: buffers stay zero.
__global__ __launch_bounds__(256)
void t0_update(uint16_t* __restrict__ h, uint16_t* __restrict__ c_out,
               const uint16_t* __restrict__ ioufx, const int* __restrict__ csr_off)
{
  const int wave = threadIdx.x >> 6, lane = threadIdx.x & 63;
  const long bs = (long)blockIdx.x*4 + wave;
  const int b = (int)(bs >> 9), s = (int)(bs & 511);
  const int j = lane * 4;
  const int* off_td = csr_off + (long)b*(S_+1);        // arr=0, t=0
  if (s == 0 || off_td[s+1] <= off_td[s]) return;      // unmasked: stay zero
  const long ib = bs*1024;
  const float4 ai = bf4(ioufx + ib + j);
  const float4 ao = bf4(ioufx + ib + 256 + j);
  const float4 au = bf4(ioufx + ib + 512 + j);
  float4 cacc;
  cacc.x = sigm(ai.x)*tanhf(au.x); cacc.y = sigm(ai.y)*tanhf(au.y);
  cacc.z = sigm(ai.z)*tanhf(au.z); cacc.w = sigm(ai.w)*tanhf(au.w);
  ushort4 ho, co;
  ho.x = f2bf(sigm(ao.x)*tanhf(cacc.x)); ho.y = f2bf(sigm(ao.y)*tanhf(cacc.y));
  ho.z = f2bf(sigm(ao.z)*tanhf(cacc.z)); ho.w = f2bf(sigm(ao.w)*tanhf(cacc.w));
  co.x = f2bf(cacc.x); co.y = f2bf(cacc.y); co.z = f2bf(cacc.z); co.w = f2bf(cacc.w);
  *reinterpret_cast<ushort4*>(h + bs*256 + j) = ho;
  *reinterpret_cast<ushort4*>(c_out + bs*256 + j) = co;
}

// ---------------------------------------------------------------------------
// Per-step destination-side update. 1 wave per row, lane owns 4 channels.
// XCD-pinned per batch-element (b's 2MB P-window stays in one L2).
// h updated IN PLACE; c ping-pongs. grid = CB*128.
__global__ __launch_bounds__(256)
void step_update(uint16_t* __restrict__ h,
                 const uint16_t* __restrict__ c_in, uint16_t* __restrict__ c_out,
                 const uint16_t* __restrict__ P,      // [Mc][2048] bf16, chunk-local rows
                 const uint16_t* __restrict__ ioufx,  // [M][1024] bf16: i|o|u|fx
                 const int* __restrict__ csr_off, const int* __restrict__ csr_val,
                 const int* __restrict__ tr_g, const int* __restrict__ tl_g,
                 int t, int row0)
{
  const int wave = threadIdx.x >> 6, lane = threadIdx.x & 63;
  const int id = blockIdx.x, rx = id & 7, q = id >> 3;
  const int b_local = rx + 8*(q >> 7);                   // [0,CB)
  const int rg = q & 127;                                // [0,128)
  const long bs = (long)row0 + b_local*512 + rg*4 + wave;
  const int b = (int)(bs >> 9), s = (int)(bs & 511);
  const int j = lane * 4;             // channel group

  const int* off_td = csr_off + (((long)0*T_ + t)*B_ + b)*(S_+1);
  const int td0 = off_td[s], td1 = off_td[s+1];
  const bool masked = (s != 0) && (td1 > td0);
  if (!masked) {
    *reinterpret_cast<ushort4*>(c_out + bs*256 + j) =
        *reinterpret_cast<const ushort4*>(c_in + bs*256 + j);
    return;                            // h unchanged (in place)
  }
  const int* off_tr = csr_off + (((long)1*T_ + t)*B_ + b)*(S_+1);
  const int* off_tl = csr_off + (((long)2*T_ + t)*B_ + b)*(S_+1);
  const int* val_td = csr_val + (((long)0*T_ + t)*B_ + b)*S_;
  const int* val_tr = csr_val + (((long)1*T_ + t)*B_ + b)*S_;
  const int* val_tl = csr_val + (((long)2*T_ + t)*B_ + b)*S_;

  const long lbase = (long)(b<<9) - row0;             // chunk-local row base for P

  const long ib = bs*1024;
  float4 ai = bf4(ioufx + ib + j);
  float4 ao = bf4(ioufx + ib + 256 + j);
  float4 au = bf4(ioufx + ib + 512 + j);
  for (int p = off_tr[s]; p < off_tr[s+1]; ++p) {     // sources s' with tr[s']==s
    const long pr = (lbase + val_tr[p]) * NP_;
    const float4 x = bf4(P + pr + j), y = bf4(P + pr + 256 + j), z = bf4(P + pr + 512 + j);
    ai.x+=x.x; ai.y+=x.y; ai.z+=x.z; ai.w+=x.w;
    ao.x+=y.x; ao.y+=y.y; ao.z+=y.z; ao.w+=y.w;
    au.x+=z.x; au.y+=z.y; au.z+=z.z; au.w+=z.w;
  }
  for (int p = off_tl[s]; p < off_tl[s+1]; ++p) {     // sources s' with tl[s']==s
    const long pr = (lbase + val_tl[p]) * NP_;
    const float4 x = bf4(P + pr + 768 + j), y = bf4(P + pr + 1024 + j), z = bf4(P + pr + 1280 + j);
    ai.x+=x.x; ai.y+=x.y; ai.z+=x.z; ai.w+=x.w;
    ao.x+=y.x; ao.y+=y.y; ao.z+=y.z; ao.w+=y.w;
    au.x+=z.x; au.y+=z.y; au.z+=z.z; au.w+=z.w;
  }
  float4 cacc;
  cacc.x = sigm(ai.x)*tanhf(au.x); cacc.y = sigm(ai.y)*tanhf(au.y);
  cacc.z = sigm(ai.z)*tanhf(au.z); cacc.w = sigm(ai.w)*tanhf(au.w);
  const float4 fxv = bf4(ioufx + ib + 768 + j);       // f_x at the DESTINATION row
  const int* trrow = tr_g + ((long)b*T_ + t)*S_;
  const int* tlrow = tl_g + ((long)b*T_ + t)*S_;
  for (int p = td0; p < td1; ++p) {                   // children s' with td[s']==s
    const int sp = val_td[p];
    const long prr = (lbase + trrow[sp]) * NP_ + 1536;  // gather P_f01 at tr[s']
    const long prl = (lbase + tlrow[sp]) * NP_ + 1792;  // gather P_f23 at tl[s']
    const float4 pa = bf4(P + prr + j), pb = bf4(P + prl + j);
    const float4 cv = bf4(c_in + ((long)(b<<9) + sp)*256 + j);
    cacc.x += sigm(fxv.x + pa.x + pb.x) * cv.x;
    cacc.y += sigm(fxv.y + pa.y + pb.y) * cv.y;
    cacc.z += sigm(fxv.z + pa.z + pb.z) * cv.z;
    cacc.w += sigm(fxv.w + pa.w + pb.w) * cv.w;
  }
  ushort4 ho, co;
  ho.x = f2bf(sigm(ao.x) * tanhf(cacc.x));
  ho.y = f2bf(sigm(ao.y) * tanhf(cacc.y));
  ho.z = f2bf(sigm(ao.z) * tanhf(cacc.z));
  ho.w = f2bf(sigm(ao.w) * tanhf(cacc.w));
  co.x = f2bf(cacc.x); co.y = f2bf(cacc.y); co.z = f2bf(cacc.z); co.w = f2bf(cacc.w);
  *reinterpret_cast<ushort4*>(h + bs*256 + j) = ho;
  *reinterpret_cast<ushort4*>(c_out + bs*256 + j) = co;
}

// ---------------------------------------------------------------------------
__global__ void root_kernel(const uint16_t* __restrict__ h, const int* __restrict__ td_g,
                            float* __restrict__ out_root){
  const int b = blockIdx.x;
  __shared__ int red[256];
  const int* td = td_g + ((long)b*T_ + (T_-1))*S_;
  int m = 0;
  for (int s = threadIdx.x; s < S_; s += 256) m = max(m, td[s]);
  red[threadIdx.x] = m; __syncthreads();
  for (int w = 128; w > 0; w >>= 1){
    if (threadIdx.x < w) red[threadIdx.x] = max(red[threadIdx.x], red[threadIdx.x+w]);
    __syncthreads();
  }
  const int root = red[0];
  out_root[b*256 + threadIdx.x] = bf2f(h[((long)b*512 + root)*256 + threadIdx.x]);
}

// ---------------------------------------------------------------------------
extern "C" void kernel_launch(void* const* d_in, const int* in_sizes, int n_in,
                              void* d_out, int out_size, void* d_ws, size_t ws_size,
                              hipStream_t stream) {
  const int*   input_ids  = (const int*)  d_in[0];
  const int*   tree_ids   = (const int*)  d_in[1];
  const int*   tree_ids_r = (const int*)  d_in[2];
  const int*   tree_ids_l = (const int*)  d_in[3];
  const float* emb        = (const float*)d_in[4];
  const float* W_ioux     = (const float*)d_in[5];
  const float* b_ioux     = (const float*)d_in[6];
  const float* W_f        = (const float*)d_in[9];
  const float* b_f        = (const float*)d_in[10];
  float* out = (float*)d_out;                  // FP32 outputs: h | c | h_root

  // --- workspace layout: fixed ~128 MB + adaptive P chunk ---
  size_t woff = 0;
  auto alloc = [&](size_t bytes)->char*{
    char* p = (char*)d_ws + woff; woff += (bytes + 255) & ~(size_t)255; return p;
  };
  uint16_t* ioufx  = (uint16_t*)alloc((size_t)M_*1024*2);     // 67.1 MB: i|o|u|fx
  uint16_t* hA     = (uint16_t*)alloc((size_t)M_*256*2);      // 16.8 MB (hA,cA,cB contiguous)
  uint16_t* cA     = (uint16_t*)alloc((size_t)M_*256*2);
  uint16_t* cB     = (uint16_t*)alloc((size_t)M_*256*2);
  int* csr_off     = (int*)     alloc((size_t)3*T_*B_*(S_+1)*4);
  int* csr_val     = (int*)     alloc((size_t)3*T_*B_*S_*4);
  uint16_t* UcatT  = (uint16_t*)alloc((size_t)NP_*256*2);     //  1.05 MB
  uint16_t* WallT  = (uint16_t*)alloc((size_t)1024*256*2);    //  0.52 MB
  int CB = 64;                                                // batches per P chunk
  while (CB > 8 && woff + (size_t)CB*S_*NP_*2 > ws_size) CB >>= 1;
  uint16_t* P      = (uint16_t*)alloc((size_t)CB*S_*NP_*2);   // <=134 MB (bf16)
  uint16_t* embg   = P;                                       // setup-only alias (16.8 MB)

  // --- setup ---
  build_ucatT<<<2048, 256, 0, stream>>>((const float*)d_in[7], (const float*)d_in[8],
      (const float*)d_in[11], (const float*)d_in[12], (const float*)d_in[13], (const float*)d_in[14],
      UcatT);
  build_wallT<<<1024, 256, 0, stream>>>(W_ioux, W_f, WallT);
  gather_embg<<<M_/4, 256, 0, stream>>>(emb, input_ids, embg);
  gemm_pipe<<<(M_/128)*8, 256, 0, stream>>>(embg, WallT, b_ioux, b_f, 768, ioufx, 1024, 8);
  build_csr<<<T_*B_, S_, 0, stream>>>(tree_ids, tree_ids_r, tree_ids_l, csr_off, csr_val);
  zero16<<<12288, 256, 0, stream>>>((uint4*)hA, 3145728L);   // zero hA+cA+cB (50.3MB)

  // --- T steps; h in place, c ping-pong; t=0 degenerate (P=0, c=0) ---
  uint16_t *cc = cA, *cn = cB;
  t0_update<<<M_/4, 256, 0, stream>>>(hA, cn, ioufx, csr_off);
  { uint16_t* tc = cc; cc = cn; cn = tc; }
  for (int t = 1; t < T_; ++t) {
    for (int b0 = 0; b0 < B_; b0 += CB) {
      const int row0 = b0 * S_;
      const int Mc   = CB * S_;
      gemm_pipe<<<(Mc/128)*16, 256, 0, stream>>>(hA + (long)row0*256, UcatT,
                                                 nullptr, nullptr, 0, P, NP_, 16);
      step_update<<<CB*128, 256, 0, stream>>>(hA, cc, cn, P, ioufx,
                                              csr_off, csr_val, tree_ids_r, tree_ids_l,
                                              t, row0);
    }
    uint16_t* tc = cc; cc = cn; cn = tc;
  }
  // 12 swaps total -> cc == cA (contiguous after hA)

  // --- outputs (fp32): h | c (single fused pass; hA,cA adjacent) | h_root ---
  bf16_to_f32<<<16384, 256, 0, stream>>>(hA, out, 2L*M_*256);                   // h then c
  root_kernel<<<B_, 256, 0, stream>>>(hA, tree_ids, out + 2L*M_*256);           // h_root
}